// Round 1
// baseline (471.135 us; speedup 1.0000x reference)
//
#include <hip/hip_runtime.h>
#include <hip/hip_bf16.h>

#define NROWS 4096
#define NCLS  10000
#define DIM   2048
#define ALPHA_F 10.0f
#define BETA_F  2.0f

typedef __bf16 bf16x8 __attribute__((ext_vector_type(8)));
typedef float  f32x4  __attribute__((ext_vector_type(4)));

__device__ __forceinline__ unsigned short f32_to_bf16_rne(float f) {
  unsigned int u = __float_as_uint(f);
  u += 0x7FFFu + ((u >> 16) & 1u);
  return (unsigned short)(u >> 16);
}

__global__ void cast_kernel(const float* __restrict__ src,
                            unsigned short* __restrict__ dst, int n4) {
  int stride = gridDim.x * blockDim.x;
  for (int i = blockIdx.x * blockDim.x + threadIdx.x; i < n4; i += stride) {
    float4 v = reinterpret_cast<const float4*>(src)[i];
    ushort4 o;
    o.x = f32_to_bf16_rne(v.x);
    o.y = f32_to_bf16_rne(v.y);
    o.z = f32_to_bf16_rne(v.z);
    o.w = f32_to_bf16_rne(v.w);
    reinterpret_cast<ushort4*>(dst)[i] = o;
  }
}

// fp32 dot(inputs_i, kernel[targets_i]) -> dotv[i]; one wave per row.
__global__ void gather_dot_kernel(const float* __restrict__ X, const float* __restrict__ Kn,
                                  const int* __restrict__ tgt, float* __restrict__ dotv) {
  int gtid = blockIdx.x * blockDim.x + threadIdx.x;
  int wave = gtid >> 6;
  int lane = threadIdx.x & 63;
  if (wave >= NROWS) return;
  const float* xr = X + (size_t)wave * DIM;
  const float* kr = Kn + (size_t)tgt[wave] * DIM;
  float s = 0.f;
#pragma unroll
  for (int it = 0; it < DIM / 256; ++it) {
    int k = lane * 4 + it * 256;
    float4 a = *reinterpret_cast<const float4*>(xr + k);
    float4 b = *reinterpret_cast<const float4*>(kr + k);
    s += a.x * b.x + a.y * b.y + a.z * b.z + a.w * b.w;
  }
#pragma unroll
  for (int off = 32; off > 0; off >>= 1) s += __shfl_down(s, off);
  if (lane == 0) dotv[wave] = s;
}

// Tiled bf16 MFMA A·B^T with fused reduction epilogue. BM=BN=128, BK=32,
// 256 threads = 4 waves in 2x2, each wave a 64x64 quadrant via 4x4 16x16x32 frags.
// EP==0: per-row stats of clip(cos): S1 += sum, Eacc += sum exp(10c), CNT += #(c>phi)
// EP==1: global sim stats: simAcc[0]+=sum(sim|same label), [1]+=sum(sim), [2]+=#same
template <int EP>
__global__ __launch_bounds__(256, 2)
void tile_reduce_kernel(const unsigned short* __restrict__ A,
                        const unsigned short* __restrict__ B,
                        int nBrows,
                        const float* __restrict__ dotv,
                        const int* __restrict__ tgt,
                        float* __restrict__ S1, float* __restrict__ Eacc,
                        float* __restrict__ CNT, float* __restrict__ simAcc) {
  __shared__ unsigned short shA[2][128 * 32];
  __shared__ unsigned short shB[2][128 * 32];
  __shared__ float redbuf[12];

  const int tid  = threadIdx.x;
  const int lane = tid & 63;
  const int wid  = tid >> 6;
  const int wr   = wid >> 1;          // wave row (0..1)
  const int wc   = wid & 1;           // wave col (0..1)
  const int fr   = lane & 15;
  const int kg   = lane >> 4;
  const int rowBase = blockIdx.y * 128;
  const int colBase = blockIdx.x * 128;

  // staging coords: thread t (0..511 over 2 issues) covers row t/4, k-cols (t%4)*8..+8
  int sRow[2], sCol[2];
#pragma unroll
  for (int iss = 0; iss < 2; ++iss) {
    int t = tid + iss * 256;
    sRow[iss] = t >> 2;
    sCol[iss] = (t & 3) << 3;
  }

  f32x4 acc[4][4];
  const f32x4 zero = {0.f, 0.f, 0.f, 0.f};
#pragma unroll
  for (int m = 0; m < 4; ++m)
#pragma unroll
    for (int n = 0; n < 4; ++n) acc[m][n] = zero;

  auto stageA = [&](int buf, int kBase) {
#pragma unroll
    for (int iss = 0; iss < 2; ++iss) {
      int gr = rowBase + sRow[iss];
      const unsigned short* gp = A + (size_t)gr * DIM + kBase + sCol[iss];
      unsigned short* lp = &shA[buf][(tid + iss * 256) * 8];
      __builtin_amdgcn_global_load_lds((const __attribute__((address_space(1))) void*)gp,
                                       (__attribute__((address_space(3))) void*)lp, 16, 0, 0);
    }
  };
  auto stageB = [&](int buf, int kBase) {
#pragma unroll
    for (int iss = 0; iss < 2; ++iss) {
      int gr = colBase + sRow[iss];
      if (gr >= nBrows) gr = nBrows - 1;   // tail clamp; masked in epilogue
      const unsigned short* gp = B + (size_t)gr * DIM + kBase + sCol[iss];
      unsigned short* lp = &shB[buf][(tid + iss * 256) * 8];
      __builtin_amdgcn_global_load_lds((const __attribute__((address_space(1))) void*)gp,
                                       (__attribute__((address_space(3))) void*)lp, 16, 0, 0);
    }
  };

  const int NKT = DIM / 32;
  stageA(0, 0);
  stageB(0, 0);
  asm volatile("s_waitcnt vmcnt(0)" ::: "memory");
  __syncthreads();

  for (int kt = 0; kt < NKT; ++kt) {
    int cur = kt & 1;
    if (kt + 1 < NKT) {
      stageA(cur ^ 1, (kt + 1) * 32);
      stageB(cur ^ 1, (kt + 1) * 32);
    }
    const unsigned short* sa = shA[cur];
    const unsigned short* sb = shB[cur];
    bf16x8 af[4], bv[4];
#pragma unroll
    for (int m = 0; m < 4; ++m)
      af[m] = *reinterpret_cast<const bf16x8*>(sa + (wr * 64 + m * 16 + fr) * 32 + kg * 8);
#pragma unroll
    for (int n = 0; n < 4; ++n)
      bv[n] = *reinterpret_cast<const bf16x8*>(sb + (wc * 64 + n * 16 + fr) * 32 + kg * 8);
#pragma unroll
    for (int m = 0; m < 4; ++m)
#pragma unroll
      for (int n = 0; n < 4; ++n)
        acc[m][n] = __builtin_amdgcn_mfma_f32_16x16x32_bf16(af[m], bv[n], acc[m][n], 0, 0, 0);
    asm volatile("s_waitcnt vmcnt(0)" ::: "memory");
    __syncthreads();
  }

  // C/D layout (m89/m91): col = lane&15 (fr), row = (lane>>4)*4 + j (kg,j)
  if (EP == 0) {
    float* shPhi = reinterpret_cast<float*>(&shA[0][0]);
    if (tid < 128) shPhi[tid] = dotv[rowBase + tid] - BETA_F;
    __syncthreads();
#pragma unroll
    for (int m = 0; m < 4; ++m) {
#pragma unroll
      for (int j = 0; j < 4; ++j) {
        int rl = wr * 64 + m * 16 + kg * 4 + j;
        float ph = shPhi[rl];
        float s1 = 0.f, ee = 0.f, ct = 0.f;
#pragma unroll
        for (int n = 0; n < 4; ++n) {
          int gcol = colBase + wc * 64 + n * 16 + fr;
          float c = acc[m][n][j];
          c = fminf(fmaxf(c, -1.f), 1.f);
          if (gcol < nBrows) {
            s1 += c;
            ee += __expf(ALPHA_F * c);
            ct += (c > ph) ? 1.f : 0.f;
          }
        }
#pragma unroll
        for (int o = 1; o < 16; o <<= 1) {
          s1 += __shfl_xor(s1, o);
          ee += __shfl_xor(ee, o);
          ct += __shfl_xor(ct, o);
        }
        if (fr == 0) {
          int grow = rowBase + rl;
          atomicAdd(&S1[grow], s1);
          atomicAdd(&Eacc[grow], ee);
          atomicAdd(&CNT[grow], ct);
        }
      }
    }
  } else {
    int* shT = reinterpret_cast<int*>(&shA[0][0]);
    if (tid < 128) shT[tid] = tgt[rowBase + tid];
    else if (tid < 256) shT[tid] = tgt[colBase + (tid - 128)];
    __syncthreads();
    float ps = 0.f, als = 0.f, pc = 0.f;
#pragma unroll
    for (int m = 0; m < 4; ++m) {
#pragma unroll
      for (int j = 0; j < 4; ++j) {
        int rl = wr * 64 + m * 16 + kg * 4 + j;
        int tr = shT[rl];
#pragma unroll
        for (int n = 0; n < 4; ++n) {
          int cl = wc * 64 + n * 16 + fr;
          float c = acc[m][n][j];   // sim is NOT clipped in the reference
          als += c;
          if (tr == shT[128 + cl]) { ps += c; pc += 1.f; }
        }
      }
    }
#pragma unroll
    for (int o = 1; o < 64; o <<= 1) {
      ps  += __shfl_xor(ps, o);
      als += __shfl_xor(als, o);
      pc  += __shfl_xor(pc, o);
    }
    if (lane == 0) {
      redbuf[wid * 3 + 0] = ps;
      redbuf[wid * 3 + 1] = als;
      redbuf[wid * 3 + 2] = pc;
    }
    __syncthreads();
    if (tid == 0) {
      float p = 0.f, a = 0.f, c2 = 0.f;
      for (int w = 0; w < 4; ++w) {
        p += redbuf[w * 3 + 0];
        a += redbuf[w * 3 + 1];
        c2 += redbuf[w * 3 + 2];
      }
      atomicAdd(&simAcc[0], p);
      atomicAdd(&simAcc[1], a);
      atomicAdd(&simAcc[2], c2);
    }
  }
}

__global__ void finalize_kernel(const float* __restrict__ dotv, const float* __restrict__ S1,
                                const float* __restrict__ Eacc, const float* __restrict__ CNT,
                                const float* __restrict__ simAcc, float* __restrict__ out) {
  __shared__ float sh[5][256];
  int tid = threadIdx.x;
  float sum_posc = 0.f, sum_s1 = 0.f, loss_sum = 0.f, mask_cnt = 0.f, correct = 0.f;
  for (int i = tid; i < NROWS; i += 256) {
    float d = dotv[i];
    float posc = fminf(fmaxf(d, -1.f), 1.f);   // pos_cos (clipped target cos)
    float phi = d - BETA_F;
    sum_posc += posc;
    sum_s1 += S1[i];
    float e = Eacc[i] - __expf(ALPHA_F * posc);   // exclude target column
    float cexcl = CNT[i] - 1.f;                   // target always counted (margin = BETA)
    float per = -phi + __logf(e) / ALPHA_F;
    if (cexcl > 0.5f) { loss_sum += per; mask_cnt += 1.f; }
    else correct += 1.f;                          // pred == target iff no non-target col > phi
  }
  sh[0][tid] = sum_posc; sh[1][tid] = sum_s1; sh[2][tid] = loss_sum;
  sh[3][tid] = mask_cnt; sh[4][tid] = correct;
  __syncthreads();
  for (int s = 128; s > 0; s >>= 1) {
    if (tid < s)
      for (int q = 0; q < 5; ++q) sh[q][tid] += sh[q][tid + s];
    __syncthreads();
  }
  if (tid == 0) {
    float posS = sh[0][0], s1S = sh[1][0], lossS = sh[2][0], maskS = sh[3][0], corr = sh[4][0];
    out[0] = lossS / fmaxf(maskS, 1.f);
    out[1] = corr / (float)NROWS;
    out[2] = posS / (float)NROWS;
    out[3] = (s1S - posS) / ((float)NROWS * (float)(NCLS - 1));
    float pos = simAcc[0], all = simAcc[1], pcnt = simAcc[2];
    out[4] = pos / pcnt;
    out[5] = (all - pos) / ((float)NROWS * (float)NROWS - pcnt);
  }
}

extern "C" void kernel_launch(void* const* d_in, const int* in_sizes, int n_in,
                              void* d_out, int out_size, void* d_ws, size_t ws_size,
                              hipStream_t stream) {
  const float* X  = (const float*)d_in[0];   // inputs  [4096][2048] f32
  const int*   tg = (const int*)d_in[1];     // targets [4096] i32
  const float* Kn = (const float*)d_in[2];   // kernel  [10000][2048] f32
  float* out = (float*)d_out;

  char* w = (char*)d_ws;
  unsigned short* bfA = (unsigned short*)w;                 // 4096*2048 bf16
  unsigned short* bfB = bfA + (size_t)NROWS * DIM;          // 10000*2048 bf16
  float* dotv   = (float*)(w + ((size_t)NROWS * DIM + (size_t)NCLS * DIM) * 2);
  float* S1     = dotv + NROWS;
  float* Eacc   = S1 + NROWS;
  float* CNT    = Eacc + NROWS;
  float* simAcc = CNT + NROWS;

  hipMemsetAsync(S1, 0, (3 * NROWS + 4) * sizeof(float), stream);

  cast_kernel<<<2048, 256, 0, stream>>>(X, bfA, NROWS * DIM / 4);
  cast_kernel<<<2048, 256, 0, stream>>>(Kn, bfB, NCLS * DIM / 4);
  gather_dot_kernel<<<NROWS / 4, 256, 0, stream>>>(X, Kn, tg, dotv);

  tile_reduce_kernel<0><<<dim3((NCLS + 127) / 128, NROWS / 128), 256, 0, stream>>>(
      bfA, bfB, NCLS, dotv, nullptr, S1, Eacc, CNT, nullptr);
  tile_reduce_kernel<1><<<dim3(NROWS / 128, NROWS / 128), 256, 0, stream>>>(
      bfA, bfA, NROWS, nullptr, tg, nullptr, nullptr, nullptr, simAcc);

  finalize_kernel<<<1, 256, 0, stream>>>(dotv, S1, Eacc, CNT, simAcc, out);
}

// Round 2
// 377.851 us; speedup vs baseline: 1.2469x; 1.2469x over previous
//
#include <hip/hip_runtime.h>
#include <hip/hip_bf16.h>

#define NROWS 4096
#define NCLS  10000
#define DIM   2048
#define ALPHA_F 10.0f
#define BETA_F  2.0f

typedef __bf16 bf16x8 __attribute__((ext_vector_type(8)));
typedef float  f32x4  __attribute__((ext_vector_type(4)));

__device__ __forceinline__ unsigned short f32_to_bf16_rne(float f) {
  unsigned int u = __float_as_uint(f);
  u += 0x7FFFu + ((u >> 16) & 1u);
  return (unsigned short)(u >> 16);
}

__global__ void cast_kernel(const float* __restrict__ src,
                            unsigned short* __restrict__ dst, int n4) {
  int stride = gridDim.x * blockDim.x;
  for (int i = blockIdx.x * blockDim.x + threadIdx.x; i < n4; i += stride) {
    float4 v = reinterpret_cast<const float4*>(src)[i];
    ushort4 o;
    o.x = f32_to_bf16_rne(v.x);
    o.y = f32_to_bf16_rne(v.y);
    o.z = f32_to_bf16_rne(v.z);
    o.w = f32_to_bf16_rne(v.w);
    reinterpret_cast<ushort4*>(dst)[i] = o;
  }
}

// fp32 dot(inputs_i, kernel[targets_i]) -> dotv[i]; one wave per row.
__global__ void gather_dot_kernel(const float* __restrict__ X, const float* __restrict__ Kn,
                                  const int* __restrict__ tgt, float* __restrict__ dotv) {
  int gtid = blockIdx.x * blockDim.x + threadIdx.x;
  int wave = gtid >> 6;
  int lane = threadIdx.x & 63;
  if (wave >= NROWS) return;
  const float* xr = X + (size_t)wave * DIM;
  const float* kr = Kn + (size_t)tgt[wave] * DIM;
  float s = 0.f;
#pragma unroll
  for (int it = 0; it < DIM / 256; ++it) {
    int k = lane * 4 + it * 256;
    float4 a = *reinterpret_cast<const float4*>(xr + k);
    float4 b = *reinterpret_cast<const float4*>(kr + k);
    s += a.x * b.x + a.y * b.y + a.z * b.z + a.w * b.w;
  }
#pragma unroll
  for (int off = 32; off > 0; off >>= 1) s += __shfl_down(s, off);
  if (lane == 0) dotv[wave] = s;
}

// ---------------------------------------------------------------------------
// 256x256 8-phase bf16 MFMA A*B^T with fused reduction epilogue (no C write).
// 512 threads = 8 waves (2M x 4N); per wave 128x64 output = acc[8][4] f32x4.
// BK=64, LDS = 2buf x (A[256][64] + B[256][64]) bf16 = 128 KiB.
// XOR swizzle: 16B-slot s of row r holds logical slot s^(r&7); gload_lds
// writes linearly so the inverse permutation is applied on the global source.
// vmcnt(4) only at phases 4/8 (counted, never 0 in main loop).
// ---------------------------------------------------------------------------

#define BAR1()  asm volatile("s_barrier" ::: "memory")
#define LGKM0() do { asm volatile("s_waitcnt lgkmcnt(0)" ::: "memory"); \
                     __builtin_amdgcn_sched_barrier(0); } while (0)
#define BAR2()  do { __builtin_amdgcn_sched_barrier(0); \
                     asm volatile("s_barrier" ::: "memory"); } while (0)
#define VMC4()  asm volatile("s_waitcnt vmcnt(4)" ::: "memory")

#define STAGE_HALF(SH, BUF, SRC, RB, H, KT, NRW)                                \
  { _Pragma("unroll")                                                           \
    for (int iss = 0; iss < 2; ++iss) {                                         \
      int lr = (H) * 128 + iss * 64 + sRow;                                     \
      int gr = (RB) + lr; if (gr > (NRW) - 1) gr = (NRW) - 1;                   \
      const unsigned short* gp = (SRC) + (size_t)gr * DIM + (KT) * 64           \
                                 + ((sSlot ^ (lr & 7)) << 3);                   \
      unsigned short* lp = &SH[BUF][lr * 64 + sSlot * 8];                       \
      __builtin_amdgcn_global_load_lds(                                         \
          (const __attribute__((address_space(1))) void*)gp,                    \
          (__attribute__((address_space(3))) void*)lp, 16, 0, 0);               \
    } }

#define READ_A(MH, BUF)                                                         \
  { _Pragma("unroll")                                                           \
    for (int m2 = 0; m2 < 4; ++m2)                                              \
      _Pragma("unroll")                                                         \
      for (int kk = 0; kk < 2; ++kk) {                                          \
        int r = wr * 128 + (MH) * 64 + m2 * 16 + fr;                            \
        int slot = (kk * 4 + kg) ^ (fr & 7);                                    \
        af[m2][kk] = *reinterpret_cast<const bf16x8*>(&shA[BUF][r * 64 + slot * 8]); \
      } }

#define READ_B(BV, NH, BUF)                                                     \
  { _Pragma("unroll")                                                           \
    for (int n2 = 0; n2 < 2; ++n2)                                              \
      _Pragma("unroll")                                                         \
      for (int kk = 0; kk < 2; ++kk) {                                          \
        int c = wc * 64 + (NH) * 32 + n2 * 16 + fr;                             \
        int slot = (kk * 4 + kg) ^ (fr & 7);                                    \
        BV[n2][kk] = *reinterpret_cast<const bf16x8*>(&shB[BUF][c * 64 + slot * 8]); \
      } }

#define MFMA_Q(MH, NH, BV)                                                      \
  { __builtin_amdgcn_s_setprio(1);                                              \
    _Pragma("unroll")                                                           \
    for (int m2 = 0; m2 < 4; ++m2)                                              \
      _Pragma("unroll")                                                         \
      for (int n2 = 0; n2 < 2; ++n2)                                            \
        _Pragma("unroll")                                                       \
        for (int kk = 0; kk < 2; ++kk)                                          \
          acc[(MH) * 4 + m2][(NH) * 2 + n2] =                                   \
              __builtin_amdgcn_mfma_f32_16x16x32_bf16(                          \
                  af[m2][kk], BV[n2][kk], acc[(MH) * 4 + m2][(NH) * 2 + n2],    \
                  0, 0, 0);                                                     \
    __builtin_amdgcn_s_setprio(0); }

template <int EP>
__global__ __launch_bounds__(512, 2)
void gemm8_kernel(const unsigned short* __restrict__ A,
                  const unsigned short* __restrict__ B,
                  int nBrows,
                  const float* __restrict__ dotv,
                  const int* __restrict__ tgt,
                  float* __restrict__ S1, float* __restrict__ Eacc,
                  float* __restrict__ CNT, float* __restrict__ simAcc) {
  __shared__ unsigned short shA[2][256 * 64];
  __shared__ unsigned short shB[2][256 * 64];
  __shared__ float redbuf[24];

  const int tid  = threadIdx.x;
  const int lane = tid & 63;
  const int wid  = tid >> 6;
  const int wr   = wid >> 2;   // 0..1
  const int wc   = wid & 3;    // 0..3
  const int fr   = lane & 15;
  const int kg   = lane >> 4;
  const int sRow  = tid >> 3;  // 0..63
  const int sSlot = tid & 7;   // 16B slot

  // bijective XCD-aware swizzle (both grids have nwg % 8 == 0)
  const int nwg = gridDim.x * gridDim.y;
  const int lin = blockIdx.y * gridDim.x + blockIdx.x;
  const int cpx = nwg >> 3;
  const int swz = (lin & 7) * cpx + (lin >> 3);
  const int rowBase = (swz / gridDim.x) * 256;
  const int colBase = (swz % gridDim.x) * 256;

  f32x4 acc[8][4];
  const f32x4 zero = {0.f, 0.f, 0.f, 0.f};
#pragma unroll
  for (int m = 0; m < 8; ++m)
#pragma unroll
    for (int n = 0; n < 4; ++n) acc[m][n] = zero;

  // prologue: tile0 -> buf0 (4 halves), B halves of tile1 -> buf1
  STAGE_HALF(shA, 0, A, rowBase, 0, 0, NROWS);
  STAGE_HALF(shA, 0, A, rowBase, 1, 0, NROWS);
  STAGE_HALF(shB, 0, B, colBase, 0, 0, nBrows);
  STAGE_HALF(shB, 0, B, colBase, 1, 0, nBrows);
  STAGE_HALF(shB, 1, B, colBase, 0, 1, nBrows);
  STAGE_HALF(shB, 1, B, colBase, 1, 1, nBrows);
  VMC4();
  BAR1();

  bf16x8 af[4][2], bvA[2][2], bvB[2][2];

#pragma unroll 1
  for (int it = 0; it < 16; ++it) {
    const int t1 = 2 * it + 1;
    int t2 = 2 * it + 2; if (t2 > 31) t2 = 31;   // tail: redundant re-stage
    int t3 = 2 * it + 3; if (t3 > 31) t3 = 31;
    // P1: quadrant (mh0,nh0) of tile 2i (buf0); stage A-lo(2i+1)->buf1
    READ_A(0, 0); READ_B(bvA, 0, 0);
    STAGE_HALF(shA, 1, A, rowBase, 0, t1, NROWS);
    BAR1(); LGKM0(); MFMA_Q(0, 0, bvA); BAR2();
    // P2: (mh0,nh1); stage A-hi(2i+1)->buf1
    READ_B(bvB, 1, 0);
    STAGE_HALF(shA, 1, A, rowBase, 1, t1, NROWS);
    BAR1(); LGKM0(); MFMA_Q(0, 1, bvB); BAR2();
    // P3: (mh1,nh0); stage B-lo(2i+2)->buf0
    READ_A(1, 0);
    STAGE_HALF(shB, 0, B, colBase, 0, t2, nBrows);
    BAR1(); LGKM0(); MFMA_Q(1, 0, bvA); BAR2();
    // P4: (mh1,nh1); stage B-hi(2i+2)->buf0; counted wait for tile 2i+1
    STAGE_HALF(shB, 0, B, colBase, 1, t2, nBrows);
    BAR1(); LGKM0(); MFMA_Q(1, 1, bvB); VMC4(); BAR2();
    // P5: quadrant (mh0,nh0) of tile 2i+1 (buf1); stage A-lo(2i+2)->buf0
    READ_A(0, 1); READ_B(bvA, 0, 1);
    STAGE_HALF(shA, 0, A, rowBase, 0, t2, NROWS);
    BAR1(); LGKM0(); MFMA_Q(0, 0, bvA); BAR2();
    // P6: (mh0,nh1); stage A-hi(2i+2)->buf0
    READ_B(bvB, 1, 1);
    STAGE_HALF(shA, 0, A, rowBase, 1, t2, NROWS);
    BAR1(); LGKM0(); MFMA_Q(0, 1, bvB); BAR2();
    // P7: (mh1,nh0); stage B-lo(2i+3)->buf1
    READ_A(1, 1);
    STAGE_HALF(shB, 1, B, colBase, 0, t3, nBrows);
    BAR1(); LGKM0(); MFMA_Q(1, 0, bvA); BAR2();
    // P8: (mh1,nh1); stage B-hi(2i+3)->buf1; counted wait for tile 2i+2
    STAGE_HALF(shB, 1, B, colBase, 1, t3, nBrows);
    BAR1(); LGKM0(); MFMA_Q(1, 1, bvB); VMC4(); BAR2();
  }

  asm volatile("s_waitcnt vmcnt(0)" ::: "memory");
  __syncthreads();

  // C/D layout: col = fr, row = kg*4 + j (m89/m91)
  if (EP == 0) {
    float* shPhi = reinterpret_cast<float*>(&shA[0][0]);
    if (tid < 256) shPhi[tid] = dotv[rowBase + tid] - BETA_F;
    __syncthreads();
#pragma unroll
    for (int m = 0; m < 8; ++m) {
#pragma unroll
      for (int j = 0; j < 4; ++j) {
        int rl = wr * 128 + m * 16 + kg * 4 + j;
        float ph = shPhi[rl];
        float s1 = 0.f, ee = 0.f, ct = 0.f;
#pragma unroll
        for (int n = 0; n < 4; ++n) {
          int gcol = colBase + wc * 64 + n * 16 + fr;
          float c = acc[m][n][j];
          c = fminf(fmaxf(c, -1.f), 1.f);
          if (gcol < nBrows) {
            s1 += c;
            ee += __expf(ALPHA_F * c);
            ct += (c > ph) ? 1.f : 0.f;
          }
        }
#pragma unroll
        for (int o = 1; o < 16; o <<= 1) {
          s1 += __shfl_xor(s1, o);
          ee += __shfl_xor(ee, o);
          ct += __shfl_xor(ct, o);
        }
        if (fr == 0) {
          int grow = rowBase + rl;
          atomicAdd(&S1[grow], s1);
          atomicAdd(&Eacc[grow], ee);
          atomicAdd(&CNT[grow], ct);
        }
      }
    }
  } else {
    int* shT = reinterpret_cast<int*>(&shA[0][0]);
    if (tid < 256) shT[tid] = tgt[rowBase + tid];
    else shT[tid] = tgt[colBase + (tid - 256)];
    __syncthreads();
    float ps = 0.f, als = 0.f, pc = 0.f;
#pragma unroll
    for (int m = 0; m < 8; ++m) {
#pragma unroll
      for (int j = 0; j < 4; ++j) {
        int rl = wr * 128 + m * 16 + kg * 4 + j;
        int tr = shT[rl];
#pragma unroll
        for (int n = 0; n < 4; ++n) {
          int cl = wc * 64 + n * 16 + fr;
          float c = acc[m][n][j];   // sim is NOT clipped in the reference
          als += c;
          if (tr == shT[256 + cl]) { ps += c; pc += 1.f; }
        }
      }
    }
#pragma unroll
    for (int o = 1; o < 64; o <<= 1) {
      ps  += __shfl_xor(ps, o);
      als += __shfl_xor(als, o);
      pc  += __shfl_xor(pc, o);
    }
    if (lane == 0) {
      redbuf[wid * 3 + 0] = ps;
      redbuf[wid * 3 + 1] = als;
      redbuf[wid * 3 + 2] = pc;
    }
    __syncthreads();
    if (tid == 0) {
      float p = 0.f, a = 0.f, c2 = 0.f;
      for (int w = 0; w < 8; ++w) {
        p += redbuf[w * 3 + 0];
        a += redbuf[w * 3 + 1];
        c2 += redbuf[w * 3 + 2];
      }
      atomicAdd(&simAcc[0], p);
      atomicAdd(&simAcc[1], a);
      atomicAdd(&simAcc[2], c2);
    }
  }
}

__global__ void finalize_kernel(const float* __restrict__ dotv, const float* __restrict__ S1,
                                const float* __restrict__ Eacc, const float* __restrict__ CNT,
                                const float* __restrict__ simAcc, float* __restrict__ out) {
  __shared__ float sh[5][256];
  int tid = threadIdx.x;
  float sum_posc = 0.f, sum_s1 = 0.f, loss_sum = 0.f, mask_cnt = 0.f, correct = 0.f;
  for (int i = tid; i < NROWS; i += 256) {
    float d = dotv[i];
    float posc = fminf(fmaxf(d, -1.f), 1.f);   // pos_cos (clipped target cos)
    float phi = d - BETA_F;
    sum_posc += posc;
    sum_s1 += S1[i];
    float e = Eacc[i] - __expf(ALPHA_F * posc);   // exclude target column
    float cexcl = CNT[i] - 1.f;                   // target always counted (margin = BETA)
    float per = -phi + __logf(e) / ALPHA_F;
    if (cexcl > 0.5f) { loss_sum += per; mask_cnt += 1.f; }
    else correct += 1.f;                          // pred == target iff no non-target col > phi
  }
  sh[0][tid] = sum_posc; sh[1][tid] = sum_s1; sh[2][tid] = loss_sum;
  sh[3][tid] = mask_cnt; sh[4][tid] = correct;
  __syncthreads();
  for (int s = 128; s > 0; s >>= 1) {
    if (tid < s)
      for (int q = 0; q < 5; ++q) sh[q][tid] += sh[q][tid + s];
    __syncthreads();
  }
  if (tid == 0) {
    float posS = sh[0][0], s1S = sh[1][0], lossS = sh[2][0], maskS = sh[3][0], corr = sh[4][0];
    out[0] = lossS / fmaxf(maskS, 1.f);
    out[1] = corr / (float)NROWS;
    out[2] = posS / (float)NROWS;
    out[3] = (s1S - posS) / ((float)NROWS * (float)(NCLS - 1));
    float pos = simAcc[0], all = simAcc[1], pcnt = simAcc[2];
    out[4] = pos / pcnt;
    out[5] = (all - pos) / ((float)NROWS * (float)NROWS - pcnt);
  }
}

extern "C" void kernel_launch(void* const* d_in, const int* in_sizes, int n_in,
                              void* d_out, int out_size, void* d_ws, size_t ws_size,
                              hipStream_t stream) {
  const float* X  = (const float*)d_in[0];   // inputs  [4096][2048] f32
  const int*   tg = (const int*)d_in[1];     // targets [4096] i32
  const float* Kn = (const float*)d_in[2];   // kernel  [10000][2048] f32
  float* out = (float*)d_out;

  char* w = (char*)d_ws;
  unsigned short* bfA = (unsigned short*)w;                 // 4096*2048 bf16
  unsigned short* bfB = bfA + (size_t)NROWS * DIM;          // 10000*2048 bf16
  float* dotv   = (float*)(w + ((size_t)NROWS * DIM + (size_t)NCLS * DIM) * 2);
  float* S1     = dotv + NROWS;
  float* Eacc   = S1 + NROWS;
  float* CNT    = Eacc + NROWS;
  float* simAcc = CNT + NROWS;

  hipMemsetAsync(S1, 0, (3 * NROWS + 4) * sizeof(float), stream);

  cast_kernel<<<2048, 256, 0, stream>>>(X, bfA, NROWS * DIM / 4);
  cast_kernel<<<2048, 256, 0, stream>>>(Kn, bfB, NCLS * DIM / 4);
  gather_dot_kernel<<<NROWS / 4, 256, 0, stream>>>(X, Kn, tg, dotv);

  // 40x16 = 640 blocks (cols padded to 10240 via clamp+mask), 16x16 = 256 blocks
  gemm8_kernel<0><<<dim3(40, 16), 512, 0, stream>>>(
      bfA, bfB, NCLS, dotv, nullptr, S1, Eacc, CNT, nullptr);
  gemm8_kernel<1><<<dim3(16, 16), 512, 0, stream>>>(
      bfA, bfA, NROWS, nullptr, tg, nullptr, nullptr, nullptr, simAcc);

  finalize_kernel<<<1, 256, 0, stream>>>(dotv, S1, Eacc, CNT, simAcc, out);
}

// Round 3
// 339.132 us; speedup vs baseline: 1.3892x; 1.1142x over previous
//
#include <hip/hip_runtime.h>
#include <hip/hip_bf16.h>

#define NROWS 4096
#define NCLS  10000
#define DIM   2048
#define ALPHA_F 10.0f
#define BETA_F  2.0f

typedef __bf16 bf16x8 __attribute__((ext_vector_type(8)));
typedef float  f32x4  __attribute__((ext_vector_type(4)));

__device__ __forceinline__ unsigned short f32_to_bf16_rne(float f) {
  unsigned int u = __float_as_uint(f);
  u += 0x7FFFu + ((u >> 16) & 1u);
  return (unsigned short)(u >> 16);
}

__global__ void cast_kernel(const float* __restrict__ src,
                            unsigned short* __restrict__ dst, int n4) {
  int stride = gridDim.x * blockDim.x;
  for (int i = blockIdx.x * blockDim.x + threadIdx.x; i < n4; i += stride) {
    float4 v = reinterpret_cast<const float4*>(src)[i];
    ushort4 o;
    o.x = f32_to_bf16_rne(v.x);
    o.y = f32_to_bf16_rne(v.y);
    o.z = f32_to_bf16_rne(v.z);
    o.w = f32_to_bf16_rne(v.w);
    reinterpret_cast<ushort4*>(dst)[i] = o;
  }
}

// fp32 dot(inputs_i, kernel[targets_i]) -> dotv[i]; one wave per row.
__global__ void gather_dot_kernel(const float* __restrict__ X, const float* __restrict__ Kn,
                                  const int* __restrict__ tgt, float* __restrict__ dotv) {
  int gtid = blockIdx.x * blockDim.x + threadIdx.x;
  int wave = gtid >> 6;
  int lane = threadIdx.x & 63;
  if (wave >= NROWS) return;
  const float* xr = X + (size_t)wave * DIM;
  const float* kr = Kn + (size_t)tgt[wave] * DIM;
  float s = 0.f;
#pragma unroll
  for (int it = 0; it < DIM / 256; ++it) {
    int k = lane * 4 + it * 256;
    float4 a = *reinterpret_cast<const float4*>(xr + k);
    float4 b = *reinterpret_cast<const float4*>(kr + k);
    s += a.x * b.x + a.y * b.y + a.z * b.z + a.w * b.w;
  }
#pragma unroll
  for (int off = 32; off > 0; off >>= 1) s += __shfl_down(s, off);
  if (lane == 0) dotv[wave] = s;
}

// ---------------------------------------------------------------------------
// 256x256 8-phase bf16 MFMA A*B^T with fused reduction epilogue (no C write).
// 512 threads = 8 waves (2M x 4N). Fragment mapping chosen so each phase
// (MH,NH) touches exactly one staged A-half and one B-half:
//   row = MH*128 + wr*64 + m2*16 + (lane-part), col = NH*128 + wc*32 + n2*16.
// Stage rotation (1 half/phase) gives 3-7 phase stage->consume leads, gated
// by vmcnt(6) at P4/P8 only. LDS XOR slot swizzle, linear gload_lds dest.
// ---------------------------------------------------------------------------

#define BAR1()  asm volatile("s_barrier" ::: "memory")
#define LGKM0() do { asm volatile("s_waitcnt lgkmcnt(0)" ::: "memory"); \
                     __builtin_amdgcn_sched_barrier(0); } while (0)
#define LGKM8() asm volatile("s_waitcnt lgkmcnt(8)" ::: "memory")
#define BAR2()  do { __builtin_amdgcn_sched_barrier(0); \
                     asm volatile("s_barrier" ::: "memory"); } while (0)
#define VMC6()  asm volatile("s_waitcnt vmcnt(6)" ::: "memory")

#define STAGE_HALF(SH, BUF, SRC, RB, H, KT, NRW)                                \
  { _Pragma("unroll")                                                           \
    for (int iss = 0; iss < 2; ++iss) {                                         \
      int lr = (H) * 128 + iss * 64 + sRow;                                     \
      int gr = (RB) + lr; if (gr > (NRW) - 1) gr = (NRW) - 1;                   \
      const unsigned short* gp = (SRC) + (size_t)gr * DIM + (KT) * 64           \
                                 + ((sSlot ^ (lr & 7)) << 3);                   \
      unsigned short* lp = &SH[BUF][lr * 64 + sSlot * 8];                       \
      __builtin_amdgcn_global_load_lds(                                         \
          (const __attribute__((address_space(1))) void*)gp,                    \
          (__attribute__((address_space(3))) void*)lp, 16, 0, 0);               \
    } }

#define READ_A(MH, BUF)                                                         \
  { _Pragma("unroll")                                                           \
    for (int m2 = 0; m2 < 4; ++m2)                                              \
      _Pragma("unroll")                                                         \
      for (int kk = 0; kk < 2; ++kk) {                                          \
        int r = (MH) * 128 + wr * 64 + m2 * 16 + fr;                            \
        int slot = (kk * 4 + kg) ^ (fr & 7);                                    \
        af[m2][kk] = *reinterpret_cast<const bf16x8*>(&shA[BUF][r * 64 + slot * 8]); \
      } }

#define READ_B(BV, NH, BUF)                                                     \
  { _Pragma("unroll")                                                           \
    for (int n2 = 0; n2 < 2; ++n2)                                              \
      _Pragma("unroll")                                                         \
      for (int kk = 0; kk < 2; ++kk) {                                          \
        int c = (NH) * 128 + wc * 32 + n2 * 16 + fr;                            \
        int slot = (kk * 4 + kg) ^ (fr & 7);                                    \
        BV[n2][kk] = *reinterpret_cast<const bf16x8*>(&shB[BUF][c * 64 + slot * 8]); \
      } }

#define MFMA_Q(MH, NH, BV)                                                      \
  { __builtin_amdgcn_s_setprio(1);                                              \
    _Pragma("unroll")                                                           \
    for (int m2 = 0; m2 < 4; ++m2)                                              \
      _Pragma("unroll")                                                         \
      for (int n2 = 0; n2 < 2; ++n2)                                            \
        _Pragma("unroll")                                                       \
        for (int kk = 0; kk < 2; ++kk)                                          \
          acc[(MH) * 4 + m2][(NH) * 2 + n2] =                                   \
              __builtin_amdgcn_mfma_f32_16x16x32_bf16(                          \
                  af[m2][kk], BV[n2][kk], acc[(MH) * 4 + m2][(NH) * 2 + n2],    \
                  0, 0, 0);                                                     \
    __builtin_amdgcn_s_setprio(0); }

template <int EP>
__global__ __launch_bounds__(512, 2)
void gemm8_kernel(const unsigned short* __restrict__ A,
                  const unsigned short* __restrict__ B,
                  int nBrows,
                  const float* __restrict__ dotv,
                  const int* __restrict__ tgt,
                  float* __restrict__ S1, float* __restrict__ Eacc,
                  float* __restrict__ CNT, float* __restrict__ simAcc) {
  __shared__ unsigned short shA[2][256 * 64];
  __shared__ unsigned short shB[2][256 * 64];
  __shared__ float redbuf[24];

  const int tid  = threadIdx.x;
  const int lane = tid & 63;
  const int wid  = tid >> 6;
  const int wr   = wid >> 2;   // 0..1
  const int wc   = wid & 3;    // 0..3
  const int fr   = lane & 15;
  const int kg   = lane >> 4;
  const int sRow  = tid >> 3;  // 0..63
  const int sSlot = tid & 7;   // 16B slot

  // XCD-aware swizzle: contiguous column-major tile chunks per XCD.
  const int lin = blockIdx.x;
  int rowTile, colTile;
  if (EP == 0) {
    int swz = (lin & 7) * 80 + (lin >> 3);   // 640 blocks, cpx=80
    colTile = swz >> 4;                      // 5 col-panels per XCD
    rowTile = swz & 15;
  } else {
    int swz = (lin & 7) * 17 + (lin >> 3);   // 136 triangle blocks, cpx=17
    int r = 0;
    while ((r + 1) * (r + 2) / 2 <= swz) ++r;
    rowTile = r;
    colTile = swz - r * (r + 1) / 2;
  }
  const int rowBase = rowTile * 256;
  const int colBase = colTile * 256;

  f32x4 acc[8][4];
  const f32x4 zero = {0.f, 0.f, 0.f, 0.f};
#pragma unroll
  for (int m = 0; m < 8; ++m)
#pragma unroll
    for (int n = 0; n < 4; ++n) acc[m][n] = zero;

  // prologue: t0 all 4 halves -> buf0; t1 A-H0,B-H0,B-H1 -> buf1 (A-H1 at P1)
  STAGE_HALF(shA, 0, A, rowBase, 0, 0, NROWS);
  STAGE_HALF(shA, 0, A, rowBase, 1, 0, NROWS);
  STAGE_HALF(shB, 0, B, colBase, 0, 0, nBrows);
  STAGE_HALF(shB, 0, B, colBase, 1, 0, nBrows);
  STAGE_HALF(shA, 1, A, rowBase, 0, 1, NROWS);
  STAGE_HALF(shB, 1, B, colBase, 0, 1, nBrows);
  STAGE_HALF(shB, 1, B, colBase, 1, 1, nBrows);
  VMC6();   // t0 complete, 3 halves of t1 in flight
  BAR1();

  bf16x8 af[4][2], bvA[2][2], bvB[2][2];

#pragma unroll 1
  for (int it = 0; it < 16; ++it) {
    const int t1 = 2 * it + 1;
    int t2 = 2 * it + 2; if (t2 > 31) t2 = 31;   // tail: redundant re-stage
    int t3 = 2 * it + 3; if (t3 > 31) t3 = 31;
    // P1: (mh0,nh0) of t0(buf0); stage A-H1(t1)->buf1 [region free since prev P7]
    READ_A(0, 0); READ_B(bvA, 0, 0);
    STAGE_HALF(shA, 1, A, rowBase, 1, t1, NROWS);
    LGKM8(); BAR1(); LGKM0(); MFMA_Q(0, 0, bvA); BAR2();
    // P2: (mh0,nh1); stage A-H0(t2)->buf0 [free after P1]
    READ_B(bvB, 1, 0);
    STAGE_HALF(shA, 0, A, rowBase, 0, t2, NROWS);
    BAR1(); LGKM0(); MFMA_Q(0, 1, bvB); BAR2();
    // P3: (mh1,nh0); stage B-H0(t2)->buf0 [free after P1]
    READ_A(1, 0);
    STAGE_HALF(shB, 0, B, colBase, 0, t2, nBrows);
    BAR1(); LGKM0(); MFMA_Q(1, 0, bvA); BAR2();
    // P4: (mh1,nh1); stage B-H1(t2)->buf0 [free after P2]; gate t1 complete
    STAGE_HALF(shB, 0, B, colBase, 1, t2, nBrows);
    BAR1(); MFMA_Q(1, 1, bvB); VMC6(); BAR2();
    // P5: (mh0,nh0) of t1(buf1); stage A-H1(t2)->buf0 [free after P3]
    READ_A(0, 1); READ_B(bvA, 0, 1);
    STAGE_HALF(shA, 0, A, rowBase, 1, t2, NROWS);
    LGKM8(); BAR1(); LGKM0(); MFMA_Q(0, 0, bvA); BAR2();
    // P6: (mh0,nh1); stage A-H0(t3)->buf1 [free after P5]
    READ_B(bvB, 1, 1);
    STAGE_HALF(shA, 1, A, rowBase, 0, t3, NROWS);
    BAR1(); LGKM0(); MFMA_Q(0, 1, bvB); BAR2();
    // P7: (mh1,nh0); stage B-H0(t3)->buf1 [free after P5]
    READ_A(1, 1);
    STAGE_HALF(shB, 1, B, colBase, 0, t3, nBrows);
    BAR1(); LGKM0(); MFMA_Q(1, 0, bvA); BAR2();
    // P8: (mh1,nh1); stage B-H1(t3)->buf1 [free after P6]; gate t2 complete
    STAGE_HALF(shB, 1, B, colBase, 1, t3, nBrows);
    BAR1(); MFMA_Q(1, 1, bvB); VMC6(); BAR2();
  }

  asm volatile("s_waitcnt vmcnt(0)" ::: "memory");
  __syncthreads();

  // C/D layout: col-in-frag = fr, row-in-frag = kg*4 + j (m89/m91)
  // global row = rowBase + (m>>2)*128 + wr*64 + (m&3)*16 + kg*4 + j
  // global col = colBase + (n>>1)*128 + wc*32 + (n&1)*16 + fr
  if (EP == 0) {
    float* shPhi = reinterpret_cast<float*>(&shA[0][0]);
    if (tid < 256) shPhi[tid] = dotv[rowBase + tid] - BETA_F;
    __syncthreads();
#pragma unroll
    for (int m = 0; m < 8; ++m) {
#pragma unroll
      for (int j = 0; j < 4; ++j) {
        int rl = (m >> 2) * 128 + wr * 64 + (m & 3) * 16 + kg * 4 + j;
        float ph = shPhi[rl];
        float s1 = 0.f, ee = 0.f, ct = 0.f;
#pragma unroll
        for (int n = 0; n < 4; ++n) {
          int gcol = colBase + (n >> 1) * 128 + wc * 32 + (n & 1) * 16 + fr;
          float c = acc[m][n][j];
          c = fminf(fmaxf(c, -1.f), 1.f);
          if (gcol < nBrows) {
            s1 += c;
            ee += __expf(ALPHA_F * c);
            ct += (c > ph) ? 1.f : 0.f;
          }
        }
#pragma unroll
        for (int o = 1; o < 16; o <<= 1) {
          s1 += __shfl_xor(s1, o);
          ee += __shfl_xor(ee, o);
          ct += __shfl_xor(ct, o);
        }
        if (fr == 0) {
          int grow = rowBase + rl;
          atomicAdd(&S1[grow], s1);
          atomicAdd(&Eacc[grow], ee);
          atomicAdd(&CNT[grow], ct);
        }
      }
    }
  } else {
    const float wgt = (rowTile == colTile) ? 1.f : 2.f;  // symmetry: off-diag x2
    int* shT = reinterpret_cast<int*>(&shA[0][0]);
    if (tid < 256) shT[tid] = tgt[rowBase + tid];
    else shT[tid] = tgt[colBase + (tid - 256)];
    __syncthreads();
    float ps = 0.f, als = 0.f, pc = 0.f;
#pragma unroll
    for (int m = 0; m < 8; ++m) {
#pragma unroll
      for (int j = 0; j < 4; ++j) {
        int rl = (m >> 2) * 128 + wr * 64 + (m & 3) * 16 + kg * 4 + j;
        int tr = shT[rl];
#pragma unroll
        for (int n = 0; n < 4; ++n) {
          int cl = (n >> 1) * 128 + wc * 32 + (n & 1) * 16 + fr;
          float c = acc[m][n][j];   // sim is NOT clipped in the reference
          als += c;
          if (tr == shT[256 + cl]) { ps += c; pc += 1.f; }
        }
      }
    }
#pragma unroll
    for (int o = 1; o < 64; o <<= 1) {
      ps  += __shfl_xor(ps, o);
      als += __shfl_xor(als, o);
      pc  += __shfl_xor(pc, o);
    }
    if (lane == 0) {
      redbuf[wid * 3 + 0] = ps;
      redbuf[wid * 3 + 1] = als;
      redbuf[wid * 3 + 2] = pc;
    }
    __syncthreads();
    if (tid == 0) {
      float p = 0.f, a = 0.f, c2 = 0.f;
      for (int w = 0; w < 8; ++w) {
        p += redbuf[w * 3 + 0];
        a += redbuf[w * 3 + 1];
        c2 += redbuf[w * 3 + 2];
      }
      atomicAdd(&simAcc[0], wgt * p);
      atomicAdd(&simAcc[1], wgt * a);
      atomicAdd(&simAcc[2], wgt * c2);
    }
  }
}

__global__ void finalize_kernel(const float* __restrict__ dotv, const float* __restrict__ S1,
                                const float* __restrict__ Eacc, const float* __restrict__ CNT,
                                const float* __restrict__ simAcc, float* __restrict__ out) {
  __shared__ float sh[5][256];
  int tid = threadIdx.x;
  float sum_posc = 0.f, sum_s1 = 0.f, loss_sum = 0.f, mask_cnt = 0.f, correct = 0.f;
  for (int i = tid; i < NROWS; i += 256) {
    float d = dotv[i];
    float posc = fminf(fmaxf(d, -1.f), 1.f);   // pos_cos (clipped target cos)
    float phi = d - BETA_F;
    sum_posc += posc;
    sum_s1 += S1[i];
    float e = Eacc[i] - __expf(ALPHA_F * posc);   // exclude target column
    float cexcl = CNT[i] - 1.f;                   // target always counted (margin = BETA)
    float per = -phi + __logf(e) / ALPHA_F;
    if (cexcl > 0.5f) { loss_sum += per; mask_cnt += 1.f; }
    else correct += 1.f;                          // pred == target iff no non-target col > phi
  }
  sh[0][tid] = sum_posc; sh[1][tid] = sum_s1; sh[2][tid] = loss_sum;
  sh[3][tid] = mask_cnt; sh[4][tid] = correct;
  __syncthreads();
  for (int s = 128; s > 0; s >>= 1) {
    if (tid < s)
      for (int q = 0; q < 5; ++q) sh[q][tid] += sh[q][tid + s];
    __syncthreads();
  }
  if (tid == 0) {
    float posS = sh[0][0], s1S = sh[1][0], lossS = sh[2][0], maskS = sh[3][0], corr = sh[4][0];
    out[0] = lossS / fmaxf(maskS, 1.f);
    out[1] = corr / (float)NROWS;
    out[2] = posS / (float)NROWS;
    out[3] = (s1S - posS) / ((float)NROWS * (float)(NCLS - 1));
    float pos = simAcc[0], all = simAcc[1], pcnt = simAcc[2];
    out[4] = pos / pcnt;
    out[5] = (all - pos) / ((float)NROWS * (float)NROWS - pcnt);
  }
}

extern "C" void kernel_launch(void* const* d_in, const int* in_sizes, int n_in,
                              void* d_out, int out_size, void* d_ws, size_t ws_size,
                              hipStream_t stream) {
  const float* X  = (const float*)d_in[0];   // inputs  [4096][2048] f32
  const int*   tg = (const int*)d_in[1];     // targets [4096] i32
  const float* Kn = (const float*)d_in[2];   // kernel  [10000][2048] f32
  float* out = (float*)d_out;

  char* w = (char*)d_ws;
  unsigned short* bfA = (unsigned short*)w;                 // 4096*2048 bf16
  unsigned short* bfB = bfA + (size_t)NROWS * DIM;          // 10000*2048 bf16
  float* dotv   = (float*)(w + ((size_t)NROWS * DIM + (size_t)NCLS * DIM) * 2);
  float* S1     = dotv + NROWS;
  float* Eacc   = S1 + NROWS;
  float* CNT    = Eacc + NROWS;
  float* simAcc = CNT + NROWS;

  hipMemsetAsync(S1, 0, (3 * NROWS + 4) * sizeof(float), stream);

  cast_kernel<<<2048, 256, 0, stream>>>(X, bfA, NROWS * DIM / 4);
  cast_kernel<<<2048, 256, 0, stream>>>(Kn, bfB, NCLS * DIM / 4);
  gather_dot_kernel<<<NROWS / 4, 256, 0, stream>>>(X, Kn, tg, dotv);

  // main: 40x16 tiles = 640 blocks (cols clamped+masked past 10000)
  gemm8_kernel<0><<<640, 512, 0, stream>>>(
      bfA, bfB, NCLS, dotv, nullptr, S1, Eacc, CNT, nullptr);
  // sim: lower-triangle 17*8=136 blocks, off-diag weighted x2 (symmetry)
  gemm8_kernel<1><<<136, 512, 0, stream>>>(
      bfA, bfA, NROWS, nullptr, tg, nullptr, nullptr, nullptr, simAcc);

  finalize_kernel<<<1, 256, 0, stream>>>(dotv, S1, Eacc, CNT, simAcc, out);
}

// Round 4
// 300.695 us; speedup vs baseline: 1.5668x; 1.1278x over previous
//
#include <hip/hip_runtime.h>
#include <hip/hip_bf16.h>

#define NROWS 4096
#define NCLS  10000
#define DIM   2048
#define ALPHA_F 10.0f
#define BETA_F  2.0f

typedef __bf16 bf16x8 __attribute__((ext_vector_type(8)));
typedef float  f32x4  __attribute__((ext_vector_type(4)));

__device__ __forceinline__ unsigned short f32_to_bf16_rne(float f) {
  unsigned int u = __float_as_uint(f);
  u += 0x7FFFu + ((u >> 16) & 1u);
  return (unsigned short)(u >> 16);
}

__global__ void cast_kernel(const float* __restrict__ src,
                            unsigned short* __restrict__ dst, int n4) {
  int stride = gridDim.x * blockDim.x;
  for (int i = blockIdx.x * blockDim.x + threadIdx.x; i < n4; i += stride) {
    float4 v = reinterpret_cast<const float4*>(src)[i];
    ushort4 o;
    o.x = f32_to_bf16_rne(v.x);
    o.y = f32_to_bf16_rne(v.y);
    o.z = f32_to_bf16_rne(v.z);
    o.w = f32_to_bf16_rne(v.w);
    reinterpret_cast<ushort4*>(dst)[i] = o;
  }
}

// fp32 dot(inputs_i, kernel[targets_i]) -> dotv[i]; one wave per row.
__global__ void gather_dot_kernel(const float* __restrict__ X, const float* __restrict__ Kn,
                                  const int* __restrict__ tgt, float* __restrict__ dotv) {
  int gtid = blockIdx.x * blockDim.x + threadIdx.x;
  int wave = gtid >> 6;
  int lane = threadIdx.x & 63;
  if (wave >= NROWS) return;
  const float* xr = X + (size_t)wave * DIM;
  const float* kr = Kn + (size_t)tgt[wave] * DIM;
  float s = 0.f;
#pragma unroll
  for (int it = 0; it < DIM / 256; ++it) {
    int k = lane * 4 + it * 256;
    float4 a = *reinterpret_cast<const float4*>(xr + k);
    float4 b = *reinterpret_cast<const float4*>(kr + k);
    s += a.x * b.x + a.y * b.y + a.z * b.z + a.w * b.w;
  }
#pragma unroll
  for (int off = 32; off > 0; off >>= 1) s += __shfl_down(s, off);
  if (lane == 0) dotv[wave] = s;
}

// ---------------------------------------------------------------------------
// 256x256 8-phase bf16 MFMA A*B^T, fused reduction epilogue (no C write).
// 512 threads = 8 waves (2M x 4N). Fragment PREFETCH ONE PHASE AHEAD:
// phase p's MFMA uses frags ds_read during phase p-1 (issued after p-1's
// MFMA cluster -> LDS pipe drains under the matrix pipe; lgkmcnt(0) at
// p-begin is nearly free). One s_barrier per phase. Stages: P2(A0+B0),
// P3(B1), P4(A1) for t+2 (buf0); P6,P7,P8 mirror for t+3 (buf1).
// vmcnt(6) gates at P3/P7 retire exactly one tile (4 halves) each, before
// the barrier that publishes them. Region overwrite rule verified: every
// stage@p targets a region last ds_read @p-2 (drained @p-1, published by
// p-1's barrier).
// ---------------------------------------------------------------------------

#define PH_BEGIN() do { asm volatile("s_waitcnt lgkmcnt(0)" ::: "memory"); \
                        __builtin_amdgcn_sched_barrier(0);                 \
                        __builtin_amdgcn_s_setprio(1); } while (0)
#define PH_MID()   do { __builtin_amdgcn_s_setprio(0);                     \
                        __builtin_amdgcn_sched_barrier(0); } while (0)
#define PH_END()   do { __builtin_amdgcn_sched_barrier(0);                 \
                        asm volatile("s_barrier" ::: "memory"); } while (0)
#define VMC6()  asm volatile("s_waitcnt vmcnt(6)" ::: "memory")
#define VMC8()  asm volatile("s_waitcnt vmcnt(8)" ::: "memory")

#define STAGE_HALF(SH, BUF, SRC, RB, H, KT, NRW)                                \
  { _Pragma("unroll")                                                           \
    for (int iss = 0; iss < 2; ++iss) {                                         \
      int lr = (H) * 128 + iss * 64 + sRow;                                     \
      int gr = (RB) + lr; if (gr > (NRW) - 1) gr = (NRW) - 1;                   \
      const unsigned short* gp = (SRC) + (size_t)gr * DIM + (KT) * 64           \
                                 + ((sSlot ^ (lr & 7)) << 3);                   \
      unsigned short* lp = &SH[BUF][lr * 64 + sSlot * 8];                       \
      __builtin_amdgcn_global_load_lds(                                         \
          (const __attribute__((address_space(1))) void*)gp,                    \
          (__attribute__((address_space(3))) void*)lp, 16, 0, 0);               \
    } }

#define READ_A(MH, BUF)                                                         \
  { _Pragma("unroll")                                                           \
    for (int m2 = 0; m2 < 4; ++m2)                                              \
      _Pragma("unroll")                                                         \
      for (int kk = 0; kk < 2; ++kk) {                                          \
        int r = (MH) * 128 + wr * 64 + m2 * 16 + fr;                            \
        int slot = (kk * 4 + kg) ^ (fr & 7);                                    \
        af[m2][kk] = *reinterpret_cast<const bf16x8*>(&shA[BUF][r * 64 + slot * 8]); \
      } }

#define READ_B(BV, NH, BUF)                                                     \
  { _Pragma("unroll")                                                           \
    for (int n2 = 0; n2 < 2; ++n2)                                              \
      _Pragma("unroll")                                                         \
      for (int kk = 0; kk < 2; ++kk) {                                          \
        int c = (NH) * 128 + wc * 32 + n2 * 16 + fr;                            \
        int slot = (kk * 4 + kg) ^ (fr & 7);                                    \
        BV[n2][kk] = *reinterpret_cast<const bf16x8*>(&shB[BUF][c * 64 + slot * 8]); \
      } }

#define MFMA_Q(MH, NH, BV)                                                      \
  { _Pragma("unroll")                                                           \
    for (int m2 = 0; m2 < 4; ++m2)                                              \
      _Pragma("unroll")                                                         \
      for (int n2 = 0; n2 < 2; ++n2)                                            \
        _Pragma("unroll")                                                       \
        for (int kk = 0; kk < 2; ++kk)                                          \
          acc[(MH) * 4 + m2][(NH) * 2 + n2] =                                   \
              __builtin_amdgcn_mfma_f32_16x16x32_bf16(                          \
                  af[m2][kk], BV[n2][kk], acc[(MH) * 4 + m2][(NH) * 2 + n2],    \
                  0, 0, 0);                                                     \
  }

template <int EP>
__global__ __launch_bounds__(512, 2)
void gemm8_kernel(const unsigned short* __restrict__ A,
                  const unsigned short* __restrict__ B,
                  int nBrows,
                  const float* __restrict__ dotv,
                  const int* __restrict__ tgt,
                  float* __restrict__ S1, float* __restrict__ Eacc,
                  float* __restrict__ CNT, float* __restrict__ simAcc) {
  __shared__ unsigned short shA[2][256 * 64];
  __shared__ unsigned short shB[2][256 * 64];
  __shared__ float redbuf[24];

  const int tid  = threadIdx.x;
  const int lane = tid & 63;
  const int wid  = tid >> 6;
  const int wr   = wid >> 2;   // 0..1
  const int wc   = wid & 3;    // 0..3
  const int fr   = lane & 15;
  const int kg   = lane >> 4;
  const int sRow  = tid >> 3;  // 0..63
  const int sSlot = tid & 7;   // 16B slot

  // XCD-aware swizzle: contiguous column-major tile chunks per XCD.
  const int lin = blockIdx.x;
  int rowTile, colTile;
  if (EP == 0) {
    int swz = (lin & 7) * 80 + (lin >> 3);   // 640 blocks, cpx=80
    colTile = swz >> 4;                      // 5 col-panels per XCD
    rowTile = swz & 15;
  } else {
    int swz = (lin & 7) * 17 + (lin >> 3);   // 136 triangle blocks, cpx=17
    int r = 0;
    while ((r + 1) * (r + 2) / 2 <= swz) ++r;
    rowTile = r;
    colTile = swz - r * (r + 1) / 2;
  }
  const int rowBase = rowTile * 256;
  const int colBase = colTile * 256;

  f32x4 acc[8][4];
  const f32x4 zero = {0.f, 0.f, 0.f, 0.f};
#pragma unroll
  for (int m = 0; m < 8; ++m)
#pragma unroll
    for (int n = 0; n < 4; ++n) acc[m][n] = zero;

  // prologue: t0 (buf0) then t1 (buf1), 8 loads each
  STAGE_HALF(shA, 0, A, rowBase, 0, 0, NROWS);
  STAGE_HALF(shA, 0, A, rowBase, 1, 0, NROWS);
  STAGE_HALF(shB, 0, B, colBase, 0, 0, nBrows);
  STAGE_HALF(shB, 0, B, colBase, 1, 0, nBrows);
  STAGE_HALF(shA, 1, A, rowBase, 0, 1, NROWS);
  STAGE_HALF(shB, 1, B, colBase, 0, 1, nBrows);
  STAGE_HALF(shB, 1, B, colBase, 1, 1, nBrows);
  STAGE_HALF(shA, 1, A, rowBase, 1, 1, NROWS);
  VMC8();                       // t0 complete (t1's 8 loads in flight)
  asm volatile("s_barrier" ::: "memory");   // publish t0 to all waves

  bf16x8 af[4][2], bvA[2][2], bvB[2][2];
  // initial prefetch for P1: af0(t0), bvA(t0)
  READ_A(0, 0); READ_B(bvA, 0, 0);

#pragma unroll 1
  for (int it = 0; it < 16; ++it) {
    int t2 = 2 * it + 2; if (t2 > 31) t2 = 31;   // tail: junk re-stage, never MFMA'd
    int t3 = 2 * it + 3; if (t3 > 31) t3 = 31;
    // P1: q(0,0) t0/buf0; prefetch bvB(t0)
    PH_BEGIN(); MFMA_Q(0, 0, bvA); PH_MID();
    READ_B(bvB, 1, 0);
    PH_END();
    // P2: q(0,1); prefetch af1(t0); stage A0(t2)+B0(t2)->buf0
    PH_BEGIN(); MFMA_Q(0, 1, bvB); PH_MID();
    READ_A(1, 0);
    STAGE_HALF(shA, 0, A, rowBase, 0, t2, NROWS);
    STAGE_HALF(shB, 0, B, colBase, 0, t2, nBrows);
    PH_END();
    // P3: q(1,0); stage B1(t2)->buf0; gate: t1 fully staged
    PH_BEGIN(); MFMA_Q(1, 0, bvA); PH_MID();
    STAGE_HALF(shB, 0, B, colBase, 1, t2, nBrows);
    VMC6();
    PH_END();
    // P4: q(1,1); prefetch af0(t1),bvA(t1) from buf1; stage A1(t2)->buf0
    PH_BEGIN(); MFMA_Q(1, 1, bvB); PH_MID();
    READ_A(0, 1); READ_B(bvA, 0, 1);
    STAGE_HALF(shA, 0, A, rowBase, 1, t2, NROWS);
    PH_END();
    // P5: q(0,0) t1/buf1; prefetch bvB(t1)
    PH_BEGIN(); MFMA_Q(0, 0, bvA); PH_MID();
    READ_B(bvB, 1, 1);
    PH_END();
    // P6: q(0,1); prefetch af1(t1); stage A0(t3)+B0(t3)->buf1
    PH_BEGIN(); MFMA_Q(0, 1, bvB); PH_MID();
    READ_A(1, 1);
    STAGE_HALF(shA, 1, A, rowBase, 0, t3, NROWS);
    STAGE_HALF(shB, 1, B, colBase, 0, t3, nBrows);
    PH_END();
    // P7: q(1,0); stage B1(t3)->buf1; gate: t2 fully staged
    PH_BEGIN(); MFMA_Q(1, 0, bvA); PH_MID();
    STAGE_HALF(shB, 1, B, colBase, 1, t3, nBrows);
    VMC6();
    PH_END();
    // P8: q(1,1); prefetch af0(t2),bvA(t2) from buf0; stage A1(t3)->buf1
    PH_BEGIN(); MFMA_Q(1, 1, bvB); PH_MID();
    READ_A(0, 0); READ_B(bvA, 0, 0);
    STAGE_HALF(shA, 1, A, rowBase, 1, t3, NROWS);
    PH_END();
  }

  asm volatile("s_waitcnt vmcnt(0) lgkmcnt(0)" ::: "memory");
  __syncthreads();

  // C/D layout: col-in-frag = fr, row-in-frag = kg*4 + j (m89/m91)
  // global row = rowBase + (m>>2)*128 + wr*64 + (m&3)*16 + kg*4 + j
  // global col = colBase + (n>>1)*128 + wc*32 + (n&1)*16 + fr
  if (EP == 0) {
    float* shPhi = reinterpret_cast<float*>(&shA[0][0]);
    if (tid < 256) shPhi[tid] = dotv[rowBase + tid] - BETA_F;
    __syncthreads();
#pragma unroll
    for (int m = 0; m < 8; ++m) {
#pragma unroll
      for (int j = 0; j < 4; ++j) {
        int rl = (m >> 2) * 128 + wr * 64 + (m & 3) * 16 + kg * 4 + j;
        float ph = shPhi[rl];
        float s1 = 0.f, ee = 0.f, ct = 0.f;
#pragma unroll
        for (int n = 0; n < 4; ++n) {
          int gcol = colBase + (n >> 1) * 128 + wc * 32 + (n & 1) * 16 + fr;
          float c = acc[m][n][j];
          c = fminf(fmaxf(c, -1.f), 1.f);
          if (gcol < nBrows) {
            s1 += c;
            ee += __expf(ALPHA_F * c);
            ct += (c > ph) ? 1.f : 0.f;
          }
        }
#pragma unroll
        for (int o = 1; o < 16; o <<= 1) {
          s1 += __shfl_xor(s1, o);
          ee += __shfl_xor(ee, o);
          ct += __shfl_xor(ct, o);
        }
        if (fr == 0) {
          int grow = rowBase + rl;
          atomicAdd(&S1[grow], s1);
          atomicAdd(&Eacc[grow], ee);
          atomicAdd(&CNT[grow], ct);
        }
      }
    }
  } else {
    const float wgt = (rowTile == colTile) ? 1.f : 2.f;  // symmetry: off-diag x2
    int* shT = reinterpret_cast<int*>(&shA[0][0]);
    if (tid < 256) shT[tid] = tgt[rowBase + tid];
    else shT[tid] = tgt[colBase + (tid - 256)];
    __syncthreads();
    float ps = 0.f, als = 0.f, pc = 0.f;
#pragma unroll
    for (int m = 0; m < 8; ++m) {
#pragma unroll
      for (int j = 0; j < 4; ++j) {
        int rl = (m >> 2) * 128 + wr * 64 + (m & 3) * 16 + kg * 4 + j;
        int tr = shT[rl];
#pragma unroll
        for (int n = 0; n < 4; ++n) {
          int cl = (n >> 1) * 128 + wc * 32 + (n & 1) * 16 + fr;
          float c = acc[m][n][j];   // sim is NOT clipped in the reference
          als += c;
          if (tr == shT[256 + cl]) { ps += c; pc += 1.f; }
        }
      }
    }
#pragma unroll
    for (int o = 1; o < 64; o <<= 1) {
      ps  += __shfl_xor(ps, o);
      als += __shfl_xor(als, o);
      pc  += __shfl_xor(pc, o);
    }
    if (lane == 0) {
      redbuf[wid * 3 + 0] = ps;
      redbuf[wid * 3 + 1] = als;
      redbuf[wid * 3 + 2] = pc;
    }
    __syncthreads();
    if (tid == 0) {
      float p = 0.f, a = 0.f, c2 = 0.f;
      for (int w = 0; w < 8; ++w) {
        p += redbuf[w * 3 + 0];
        a += redbuf[w * 3 + 1];
        c2 += redbuf[w * 3 + 2];
      }
      atomicAdd(&simAcc[0], wgt * p);
      atomicAdd(&simAcc[1], wgt * a);
      atomicAdd(&simAcc[2], wgt * c2);
    }
  }
}

__global__ void finalize_kernel(const float* __restrict__ dotv, const float* __restrict__ S1,
                                const float* __restrict__ Eacc, const float* __restrict__ CNT,
                                const float* __restrict__ simAcc, float* __restrict__ out) {
  __shared__ float sh[5][256];
  int tid = threadIdx.x;
  float sum_posc = 0.f, sum_s1 = 0.f, loss_sum = 0.f, mask_cnt = 0.f, correct = 0.f;
  for (int i = tid; i < NROWS; i += 256) {
    float d = dotv[i];
    float posc = fminf(fmaxf(d, -1.f), 1.f);   // pos_cos (clipped target cos)
    float phi = d - BETA_F;
    sum_posc += posc;
    sum_s1 += S1[i];
    float e = Eacc[i] - __expf(ALPHA_F * posc);   // exclude target column
    float cexcl = CNT[i] - 1.f;                   // target always counted (margin = BETA)
    float per = -phi + __logf(e) / ALPHA_F;
    if (cexcl > 0.5f) { loss_sum += per; mask_cnt += 1.f; }
    else correct += 1.f;                          // pred == target iff no non-target col > phi
  }
  sh[0][tid] = sum_posc; sh[1][tid] = sum_s1; sh[2][tid] = loss_sum;
  sh[3][tid] = mask_cnt; sh[4][tid] = correct;
  __syncthreads();
  for (int s = 128; s > 0; s >>= 1) {
    if (tid < s)
      for (int q = 0; q < 5; ++q) sh[q][tid] += sh[q][tid + s];
    __syncthreads();
  }
  if (tid == 0) {
    float posS = sh[0][0], s1S = sh[1][0], lossS = sh[2][0], maskS = sh[3][0], corr = sh[4][0];
    out[0] = lossS / fmaxf(maskS, 1.f);
    out[1] = corr / (float)NROWS;
    out[2] = posS / (float)NROWS;
    out[3] = (s1S - posS) / ((float)NROWS * (float)(NCLS - 1));
    float pos = simAcc[0], all = simAcc[1], pcnt = simAcc[2];
    out[4] = pos / pcnt;
    out[5] = (all - pos) / ((float)NROWS * (float)NROWS - pcnt);
  }
}

extern "C" void kernel_launch(void* const* d_in, const int* in_sizes, int n_in,
                              void* d_out, int out_size, void* d_ws, size_t ws_size,
                              hipStream_t stream) {
  const float* X  = (const float*)d_in[0];   // inputs  [4096][2048] f32
  const int*   tg = (const int*)d_in[1];     // targets [4096] i32
  const float* Kn = (const float*)d_in[2];   // kernel  [10000][2048] f32
  float* out = (float*)d_out;

  char* w = (char*)d_ws;
  unsigned short* bfA = (unsigned short*)w;                 // 4096*2048 bf16
  unsigned short* bfB = bfA + (size_t)NROWS * DIM;          // 10000*2048 bf16
  float* dotv   = (float*)(w + ((size_t)NROWS * DIM + (size_t)NCLS * DIM) * 2);
  float* S1     = dotv + NROWS;
  float* Eacc   = S1 + NROWS;
  float* CNT    = Eacc + NROWS;
  float* simAcc = CNT + NROWS;

  hipMemsetAsync(S1, 0, (3 * NROWS + 4) * sizeof(float), stream);

  cast_kernel<<<2048, 256, 0, stream>>>(X, bfA, NROWS * DIM / 4);
  cast_kernel<<<2048, 256, 0, stream>>>(Kn, bfB, NCLS * DIM / 4);
  gather_dot_kernel<<<NROWS / 4, 256, 0, stream>>>(X, Kn, tg, dotv);

  // main: 40x16 tiles = 640 blocks (cols clamped+masked past 10000)
  gemm8_kernel<0><<<640, 512, 0, stream>>>(
      bfA, bfB, NCLS, dotv, nullptr, S1, Eacc, CNT, nullptr);
  // sim: lower-triangle 17*8=136 blocks, off-diag weighted x2 (symmetry)
  gemm8_kernel<1><<<136, 512, 0, stream>>>(
      bfA, bfA, NROWS, nullptr, tg, nullptr, nullptr, nullptr, simAcc);

  finalize_kernel<<<1, 256, 0, stream>>>(dotv, S1, Eacc, CNT, simAcc, out);
}